// Round 2
// baseline (1326.371 us; speedup 1.0000x reference)
//
#include <hip/hip_runtime.h>
#include <hip/hip_bf16.h>

// Problem constants
#define Bb 4
#define Tt 4096
#define Dd 2048
#define Mm (Bb*Tt)          // 16384 rows; note M*N*K == 4096^3 exactly
#define CHUNK 64
#define NCHUNK (Tt/CHUNK)
#define NT (Dd/32)          // 64 K-tiles for gemm256

typedef short  short8  __attribute__((ext_vector_type(8)));
typedef float  floatx4 __attribute__((ext_vector_type(4)));

static __device__ __forceinline__ short f2bf(float f) {
    union { float f; unsigned u; } x; x.f = f;
    unsigned r = x.u + 0x7fffu + ((x.u >> 16) & 1u);   // RNE
    return (short)(r >> 16);
}
static __device__ __forceinline__ float bf2f(short s) {
    union { unsigned u; float f; } x; x.u = ((unsigned)(unsigned short)s) << 16;
    return x.f;
}
static __device__ __forceinline__ float siluf(float v) { return v / (1.f + __expf(-v)); }
static __device__ __forceinline__ float mixf(float xv, float sv, float tv) {
    return fmaf(tv, xv - sv, sv);    // x*t + s*(1-t)
}

// async global->LDS, 16B per lane, dest = wave-uniform base + lane*16
#define GLDS16(gp, lp) __builtin_amdgcn_global_load_lds( \
    (const __attribute__((address_space(1))) void*)(gp), \
    (__attribute__((address_space(3))) void*)(lp), 16, 0, 0)

#define FENCE() asm volatile("" ::: "memory")
#define BAR()   do { FENCE(); __builtin_amdgcn_s_barrier(); FENCE(); } while (0)
#define WAIT_LGKM0() asm volatile("s_waitcnt lgkmcnt(0)" ::: "memory")
#define WAIT_VM8()   asm volatile("s_waitcnt vmcnt(8)" ::: "memory")
#define WAIT_VM0()   asm volatile("s_waitcnt vmcnt(0)" ::: "memory")

static __device__ __forceinline__ short8 pack8(float4 a, float4 b) {
    short8 r;
    r[0]=f2bf(a.x); r[1]=f2bf(a.y); r[2]=f2bf(a.z); r[3]=f2bf(a.w);
    r[4]=f2bf(b.x); r[5]=f2bf(b.y); r[6]=f2bf(b.z); r[7]=f2bf(b.w);
    return r;
}

// ---- prep: weights fp32 -> bf16 (once) ----
__global__ __launch_bounds__(256)
void prep_w(const float* __restrict__ w0, const float* __restrict__ w1,
            const float* __restrict__ w2, const float* __restrict__ w3,
            short* __restrict__ o0, short* __restrict__ o1,
            short* __restrict__ o2, short* __restrict__ o3)
{
    const float* s; short* d;
    switch (blockIdx.y) {
        case 0: s = w0; d = o0; break;
        case 1: s = w1; d = o1; break;
        case 2: s = w2; d = o2; break;
        default: s = w3; d = o3; break;
    }
    const size_t e = ((size_t)blockIdx.x * 256 + threadIdx.x) * 8;
    float4 a = *(const float4*)(s + e);
    float4 b = *(const float4*)(s + e + 4);
    *(short8*)(d + e) = pack8(a, b);
}

// ---- prep: A-operands (mix / silu(mix)) fp32 -> bf16 (once) ----
__global__ __launch_bounds__(256)
void prep_a(const float* __restrict__ x,
            const float* __restrict__ tmk, const float* __restrict__ tmv,
            const float* __restrict__ tmr,
            short* __restrict__ ka, short* __restrict__ va, short* __restrict__ ra)
{
    const size_t e = ((size_t)blockIdx.x * 256 + threadIdx.x) * 8;
    const size_t row = e >> 11;            // / Dd
    const int    col = (int)(e & (Dd - 1));
    const int    t   = (int)(row & (Tt - 1));

    const float* xp = x + e;
    float4 x0 = *(const float4*)xp, x1 = *(const float4*)(xp + 4);
    float4 s0 = make_float4(0,0,0,0), s1 = make_float4(0,0,0,0);
    if (t > 0) { s0 = *(const float4*)(xp - Dd); s1 = *(const float4*)(xp - Dd + 4); }

    float4 tk0 = *(const float4*)(tmk + col), tk1 = *(const float4*)(tmk + col + 4);
    float4 tv0 = *(const float4*)(tmv + col), tv1 = *(const float4*)(tmv + col + 4);
    float4 tr0 = *(const float4*)(tmr + col), tr1 = *(const float4*)(tmr + col + 4);

    float4 k0 = make_float4(mixf(x0.x,s0.x,tk0.x), mixf(x0.y,s0.y,tk0.y),
                            mixf(x0.z,s0.z,tk0.z), mixf(x0.w,s0.w,tk0.w));
    float4 k1 = make_float4(mixf(x1.x,s1.x,tk1.x), mixf(x1.y,s1.y,tk1.y),
                            mixf(x1.z,s1.z,tk1.z), mixf(x1.w,s1.w,tk1.w));
    float4 v0 = make_float4(mixf(x0.x,s0.x,tv0.x), mixf(x0.y,s0.y,tv0.y),
                            mixf(x0.z,s0.z,tv0.z), mixf(x0.w,s0.w,tv0.w));
    float4 v1 = make_float4(mixf(x1.x,s1.x,tv1.x), mixf(x1.y,s1.y,tv1.y),
                            mixf(x1.z,s1.z,tv1.z), mixf(x1.w,s1.w,tv1.w));
    float4 r0 = make_float4(siluf(mixf(x0.x,s0.x,tr0.x)), siluf(mixf(x0.y,s0.y,tr0.y)),
                            siluf(mixf(x0.z,s0.z,tr0.z)), siluf(mixf(x0.w,s0.w,tr0.w)));
    float4 r1 = make_float4(siluf(mixf(x1.x,s1.x,tr1.x)), siluf(mixf(x1.y,s1.y,tr1.y)),
                            siluf(mixf(x1.z,s1.z,tr1.z)), siluf(mixf(x1.w,s1.w,tr1.w)));

    *(short8*)(ka + e) = pack8(k0, k1);
    *(short8*)(va + e) = pack8(v0, v1);
    *(short8*)(ra + e) = pack8(r0, r1);
}

// ---- 256x256 deep-pipelined bf16 GEMM (T1+T2+T3+T4+T5) ----
// C[m][n] = sum_k A[m][k]*B[n][k] + bias[n]; A: MxK, B: NxK row-major bf16.
// BK=32, 4-deep LDS ring (128 KiB), 8 waves (2Mx4N), 2 phases/K-tile x16 MFMA,
// stage tile t+3 during tile t, vmcnt(8) once per tile (never 0 in main loop).
// LDS XOR-swizzle: phys = logical ^ (((logical>>7)&7)<<4)  (involution, 16B-granular,
// mask bits 4..6 — bit 6 is a row bit, so the offset MUST be composed with XOR,
// never '+': rA*64 + (fq*16 ^ mask) carries into bit 7 when rA is odd (the R1 bug).
// global_load_lds writes linearly -> pre-swizzle the GLOBAL source per rule #21.
template<int OUTBF>
__global__ __launch_bounds__(512)
void gemm256(const short* __restrict__ A, const short* __restrict__ B,
             const float* __restrict__ bias, void* __restrict__ Cout)
{
    __shared__ short As[4*8192];   // 4 bufs x 256x32 bf16 = 64 KB
    __shared__ short Bs[4*8192];   // 64 KB

    const int tid  = threadIdx.x;
    const int lane = tid & 63, wv = tid >> 6;

    // XCD-aware bijective swizzle: 512 wgs = 8 XCDs x 64; each XCD owns one N-panel
    const int orig = blockIdx.x;
    const int wg   = (orig & 7) * 64 + (orig >> 3);
    const int row0 = (wg & 63) * 256;
    const int col0 = (wg >> 6) * 256;

    // staging decode: lane writes phys = chunk + lane*16 (linear), so it must
    // fetch the logical element phys ^ swz. mask = (lane>>3)<<4 (const per lane).
    const int lofs  = (lane * 16) ^ ((lane >> 3) << 4);   // logical byte in 1KB chunk
    const int lrow  = lofs >> 6;                          // 0..15
    const int lcol8 = (lofs >> 4) & 3;                    // 16B slot in 64B row
    const short* Ag = A + (size_t)(row0 + wv * 32 + lrow) * Dd + lcol8 * 8;
    const short* Bg = B + (size_t)(col0 + wv * 32 + lrow) * Dd + lcol8 * 8;
    short* Asw = As + wv * 1024;   // wave-uniform LDS base (shorts); +512 = 2nd 1KB chunk
    short* Bsw = Bs + wv * 1024;

#define STAGE_A(bufi) do { \
    GLDS16(Ag,                 Asw + (bufi)*8192); \
    GLDS16(Ag + (size_t)16*Dd, Asw + (bufi)*8192 + 512); \
    Ag += 32; } while (0)
#define STAGE_B(bufi) do { \
    GLDS16(Bg,                 Bsw + (bufi)*8192); \
    GLDS16(Bg + (size_t)16*Dd, Bsw + (bufi)*8192 + 512); \
    Bg += 32; } while (0)

    // frag-read bases: phys = (row*64 | fq*16) ^ mask, mask = ((row>>1)&7)<<4.
    // XOR-composed (mask bit 6 overlaps the row-bit). mask is invariant under
    // row -> row+16i, so +i*1024 / +bi*16384 strides commute with the swizzle.
    const int fm = lane & 15, fq = lane >> 4;
    const int wm = (wv >> 2) * 128;     // 0 / 128
    const int wn = (wv & 3) * 64;       // 0 / 64 / 128 / 192
    const int rA = wm + fm, rB = wn + fm;
    const char* aP = (const char*)As + (((rA * 64) | (fq * 16)) ^ (((rA >> 1) & 7) << 4));
    const char* bP = (const char*)Bs + (((rB * 64) | (fq * 16)) ^ (((rB >> 1) & 7) << 4));

    floatx4 acc[8][4];
    #pragma unroll
    for (int i = 0; i < 8; i++)
        #pragma unroll
        for (int j = 0; j < 4; j++) acc[i][j] = (floatx4){0.f,0.f,0.f,0.f};

    short8 a_[4], b_[4];

    // prologue: stage tiles 0,1,2 (12 loads/wave); vmcnt(8) lands tile 0
    STAGE_A(0); STAGE_B(0);
    STAGE_A(1); STAGE_B(1);
    STAGE_A(2); STAGE_B(2);
    WAIT_VM8();
    BAR();

    for (int t = 0; t < NT - 3; ++t) {
        const int bi = t & 3, nb = (t + 3) & 3;   // nb == (t-1)&3: fully read last iter
        // ---- phase 0: read B(all)+A(m0..3), stage A(t+3), MFMA upper half ----
        #pragma unroll
        for (int j = 0; j < 4; j++) b_[j] = *(const short8*)(bP + bi * 16384 + j * 1024);
        #pragma unroll
        for (int i = 0; i < 4; i++) a_[i] = *(const short8*)(aP + bi * 16384 + i * 1024);
        STAGE_A(nb);
        BAR();
        WAIT_LGKM0(); __builtin_amdgcn_sched_barrier(0);
        __builtin_amdgcn_s_setprio(1);
        #pragma unroll
        for (int i = 0; i < 4; i++)
            #pragma unroll
            for (int j = 0; j < 4; j++)
                acc[i][j] = __builtin_amdgcn_mfma_f32_16x16x32_bf16(a_[i], b_[j], acc[i][j], 0, 0, 0);
        __builtin_amdgcn_s_setprio(0);
        BAR();
        // ---- phase 1: read A(m4..7), stage B(t+3), vmcnt(8) gates tile t+1 ----
        #pragma unroll
        for (int i = 0; i < 4; i++) a_[i] = *(const short8*)(aP + bi * 16384 + (4 + i) * 1024);
        STAGE_B(nb);
        WAIT_VM8();   // retires through tile t+1; t+2,t+3 (8 loads) stay in flight
        BAR();
        WAIT_LGKM0(); __builtin_amdgcn_sched_barrier(0);
        __builtin_amdgcn_s_setprio(1);
        #pragma unroll
        for (int i = 0; i < 4; i++)
            #pragma unroll
            for (int j = 0; j < 4; j++)
                acc[4+i][j] = __builtin_amdgcn_mfma_f32_16x16x32_bf16(a_[i], b_[j], acc[4+i][j], 0, 0, 0);
        __builtin_amdgcn_s_setprio(0);
        BAR();
    }

    // tail: everything staged; drain once, then 3 stage-free tiles
    WAIT_VM0();
    BAR();
    for (int t = NT - 3; t < NT; ++t) {
        const int bi = t & 3;
        #pragma unroll
        for (int j = 0; j < 4; j++) b_[j] = *(const short8*)(bP + bi * 16384 + j * 1024);
        #pragma unroll
        for (int i = 0; i < 4; i++) a_[i] = *(const short8*)(aP + bi * 16384 + i * 1024);
        BAR();
        WAIT_LGKM0(); __builtin_amdgcn_sched_barrier(0);
        __builtin_amdgcn_s_setprio(1);
        #pragma unroll
        for (int i = 0; i < 4; i++)
            #pragma unroll
            for (int j = 0; j < 4; j++)
                acc[i][j] = __builtin_amdgcn_mfma_f32_16x16x32_bf16(a_[i], b_[j], acc[i][j], 0, 0, 0);
        __builtin_amdgcn_s_setprio(0);
        BAR();
        #pragma unroll
        for (int i = 0; i < 4; i++) a_[i] = *(const short8*)(aP + bi * 16384 + (4 + i) * 1024);
        BAR();
        WAIT_LGKM0(); __builtin_amdgcn_sched_barrier(0);
        __builtin_amdgcn_s_setprio(1);
        #pragma unroll
        for (int i = 0; i < 4; i++)
            #pragma unroll
            for (int j = 0; j < 4; j++)
                acc[4+i][j] = __builtin_amdgcn_mfma_f32_16x16x32_bf16(a_[i], b_[j], acc[4+i][j], 0, 0, 0);
        __builtin_amdgcn_s_setprio(0);
        BAR();
    }
#undef STAGE_A
#undef STAGE_B

    // epilogue: C/D layout col=lane&15, row=(lane>>4)*4+r
    #pragma unroll
    for (int j = 0; j < 4; j++) {
        const int gc = col0 + wn + j*16 + fm;
        const float bj = bias[gc];
        #pragma unroll
        for (int i = 0; i < 8; i++) {
            const int gr = row0 + wm + i*16 + fq*4;
            #pragma unroll
            for (int r = 0; r < 4; r++) {
                const float v = acc[i][j][r] + bj;
                if constexpr (OUTBF)
                    ((short*)Cout)[(size_t)(gr + r) * Dd + gc] = f2bf(v);
                else
                    ((float*)Cout)[(size_t)(gr + r) * Dd + gc] = v;
            }
        }
    }
}

// ---------------- chunked WKV scan (K/V/R bf16), 8 channels/thread ----------------
__global__ __launch_bounds__(256)
void scan1(const short* __restrict__ K, const short* __restrict__ V,
           const float* __restrict__ u, const float* __restrict__ w,
           float* __restrict__ Asum, float* __restrict__ Bsum, float* __restrict__ Dsum)
{
    const int c = blockIdx.x, b = blockIdx.y;
    const int d0 = threadIdx.x * 8;
    float uu[8], ww[8], a[8], bb[8], dd[8];
    #pragma unroll
    for (int e = 0; e < 8; e++) { uu[e]=u[d0+e]; ww[e]=w[d0+e]; a[e]=0.f; bb[e]=0.f; dd[e]=1.f; }
    const size_t base = ((size_t)(b*Tt + c*CHUNK)) * Dd + d0;
    #pragma unroll 2
    for (int t = 0; t < CHUNK; t++) {
        short8 kv = *(const short8*)(K + base + (size_t)t*Dd);
        short8 vv = *(const short8*)(V + base + (size_t)t*Dd);
        #pragma unroll
        for (int e = 0; e < 8; e++) {
            const float k = bf2f(kv[e]), v = bf2f(vv[e]);
            const float tt = fmaxf(uu[e] + k, ww[e]);
            const float e1 = __expf(-ww[e] - tt);
            const float e2 = __expf(uu[e] + k - tt);
            a[e]  = e1*a[e]  + e2*v;
            bb[e] = e1*bb[e] + e2;
            dd[e] *= e1;
        }
    }
    const size_t idx = ((size_t)c*Bb + b) * Dd + d0;
    #pragma unroll
    for (int e = 0; e < 8; e++) { Asum[idx+e]=a[e]; Bsum[idx+e]=bb[e]; Dsum[idx+e]=dd[e]; }
}

__global__ __launch_bounds__(256)
void scan2(const float* __restrict__ Asum, const float* __restrict__ Bsum,
           const float* __restrict__ Dsum, float* __restrict__ Sa, float* __restrict__ Sb)
{
    const int g = blockIdx.x * 256 + threadIdx.x;   // (b,d) channel: 0..8191
    float a = 0.f, bb = 0.f;
    for (int c = 0; c < NCHUNK; c++) {
        const size_t idx = (size_t)c * (Bb*Dd) + g;
        Sa[idx] = a; Sb[idx] = bb;
        const float dd = Dsum[idx];
        a  = dd*a  + Asum[idx];
        bb = dd*bb + Bsum[idx];
    }
}

__global__ __launch_bounds__(256)
void scan3(const short* __restrict__ K, const short* __restrict__ V,
           const short* __restrict__ R,
           const float* __restrict__ Sa, const float* __restrict__ Sb,
           const float* __restrict__ u, const float* __restrict__ w,
           short* __restrict__ AF)
{
    const int c = blockIdx.x, b = blockIdx.y;
    const int d0 = threadIdx.x * 8;
    float uu[8], ww[8], a[8], bb[8];
    const size_t sidx = ((size_t)c*Bb + b) * Dd + d0;
    #pragma unroll
    for (int e = 0; e < 8; e++) { uu[e]=u[d0+e]; ww[e]=w[d0+e]; a[e]=Sa[sidx+e]; bb[e]=Sb[sidx+e]; }
    const size_t base = ((size_t)(b*Tt + c*CHUNK)) * Dd + d0;
    #pragma unroll 2
    for (int t = 0; t < CHUNK; t++) {
        short8 kv = *(const short8*)(K + base + (size_t)t*Dd);
        short8 vv = *(const short8*)(V + base + (size_t)t*Dd);
        short8 rv = *(const short8*)(R + base + (size_t)t*Dd);
        short8 ov;
        #pragma unroll
        for (int e = 0; e < 8; e++) {
            const float k = bf2f(kv[e]), v = bf2f(vv[e]);
            const float tt = fmaxf(uu[e] + k, ww[e]);
            const float e1 = __expf(-ww[e] - tt);
            const float e2 = __expf(uu[e] + k - tt);
            a[e]  = e1*a[e]  + e2*v;
            bb[e] = e1*bb[e] + e2;
            ov[e] = f2bf((a[e] / bb[e]) * bf2f(rv[e]));
        }
        *(short8*)(AF + base + (size_t)t*Dd) = ov;
    }
}

extern "C" void kernel_launch(void* const* d_in, const int* in_sizes, int n_in,
                              void* d_out, int out_size, void* d_ws, size_t ws_size,
                              hipStream_t stream)
{
    const float* x   = (const float*)d_in[0];
    const float* Wk  = (const float*)d_in[1];
    const float* bk  = (const float*)d_in[2];
    const float* Wv  = (const float*)d_in[3];
    const float* bv  = (const float*)d_in[4];
    const float* Wr  = (const float*)d_in[5];
    const float* br  = (const float*)d_in[6];
    const float* Wo  = (const float*)d_in[7];
    const float* bo  = (const float*)d_in[8];
    const float* tmk = (const float*)d_in[9];
    const float* tmv = (const float*)d_in[10];
    const float* tmr = (const float*)d_in[11];
    const float* u   = (const float*)d_in[12];
    const float* w   = (const float*)d_in[13];

    char* ws = (char*)d_ws;
    short* Wkb  = (short*)(ws + 0x00000000ull);   // 8 MB each
    short* Wvb  = (short*)(ws + 0x00800000ull);
    short* Wrb  = (short*)(ws + 0x01000000ull);
    short* Wob  = (short*)(ws + 0x01800000ull);
    short* ka   = (short*)(ws + 0x02000000ull);   // 64 MB each (M x D bf16)
    short* va   = (short*)(ws + 0x06000000ull);
    short* ra   = (short*)(ws + 0x0A000000ull);
    short* Kb   = (short*)(ws + 0x0E000000ull);
    short* Vb   = (short*)(ws + 0x12000000ull);
    short* Rb   = (short*)(ws + 0x16000000ull);
    float* Asum = (float*)(ws + 0x1A000000ull);   // 2 MB each
    float* Bsum = (float*)(ws + 0x1A200000ull);
    float* Dsum = (float*)(ws + 0x1A400000ull);
    float* Sa   = (float*)(ws + 0x1A600000ull);
    float* Sb   = (float*)(ws + 0x1A800000ull);
    short* AF   = ka;   // ka is dead after the K-projection GEMM; reuse for wkv*r

    prep_w<<<dim3(2048, 4), 256, 0, stream>>>(Wk, Wv, Wr, Wo, Wkb, Wvb, Wrb, Wob);
    prep_a<<<dim3(16384), 256, 0, stream>>>(x, tmk, tmv, tmr, ka, va, ra);

    dim3 gg((Mm/256) * (Dd/256));   // 64 x 8 = 512 wgs
    gemm256<1><<<gg, 512, 0, stream>>>(ka, Wkb, bk, Kb);
    gemm256<1><<<gg, 512, 0, stream>>>(va, Wvb, bv, Vb);
    gemm256<1><<<gg, 512, 0, stream>>>(ra, Wrb, br, Rb);

    scan1<<<dim3(NCHUNK, Bb), 256, 0, stream>>>(Kb, Vb, u, w, Asum, Bsum, Dsum);
    scan2<<<dim3((Bb*Dd)/256), 256, 0, stream>>>(Asum, Bsum, Dsum, Sa, Sb);
    scan3<<<dim3(NCHUNK, Bb), 256, 0, stream>>>(Kb, Vb, Rb, Sa, Sb, u, w, AF);

    gemm256<0><<<gg, 512, 0, stream>>>(AF, Wob, bo, (float*)d_out);
}